// Round 5
// baseline (3383.649 us; speedup 1.0000x reference)
//
#include <hip/hip_runtime.h>
#include <math.h>

#define BB 32
#define NN 2048
#define DD 512
#define VV 32000
#define NSTEP 31

__device__ inline float sigm(float x){ return 1.0f/(1.0f+expf(-x)); }
__device__ inline float dot4(float4 a, float4 b){
  return a.x*b.x + a.y*b.y + a.z*b.z + a.w*b.w;
}

// Merged 8-way wave reduction: returns, in every lane, the full 64-lane sum
// of a_{lane&7}.
__device__ inline float red8(float a0,float a1,float a2,float a3,
                             float a4,float a5,float a6,float a7,int lane){
  float m01 = ((lane&1)? a1:a0) + __shfl_xor(((lane&1)? a0:a1),1,64);
  float m23 = ((lane&1)? a3:a2) + __shfl_xor(((lane&1)? a2:a3),1,64);
  float m45 = ((lane&1)? a5:a4) + __shfl_xor(((lane&1)? a4:a5),1,64);
  float m67 = ((lane&1)? a7:a6) + __shfl_xor(((lane&1)? a6:a7),1,64);
  float m03 = ((lane&2)? m23:m01) + __shfl_xor(((lane&2)? m01:m23),2,64);
  float m47 = ((lane&2)? m67:m45) + __shfl_xor(((lane&2)? m45:m67),2,64);
  float m   = ((lane&4)? m47:m03) + __shfl_xor(((lane&4)? m03:m47),4,64);
  m += __shfl_xor(m,8,64); m += __shfl_xor(m,16,64); m += __shfl_xor(m,32,64);
  return m;
}

// Device-scope grid barrier (rocPRIM-style): fence + agent atomics.
__device__ inline void grid_barrier(int* cnt, int* gen, int nblk) {
  __threadfence();
  __syncthreads();
  if (threadIdx.x == 0) {
    int g = __hip_atomic_load(gen, __ATOMIC_ACQUIRE, __HIP_MEMORY_SCOPE_AGENT);
    int a = __hip_atomic_fetch_add(cnt, 1, __ATOMIC_ACQ_REL,
                                   __HIP_MEMORY_SCOPE_AGENT) + 1;
    if (a == nblk) {
      __hip_atomic_store(cnt, 0, __ATOMIC_RELAXED, __HIP_MEMORY_SCOPE_AGENT);
      __hip_atomic_fetch_add(gen, 1, __ATOMIC_RELEASE,
                             __HIP_MEMORY_SCOPE_AGENT);
    } else {
      while (__hip_atomic_load(gen, __ATOMIC_ACQUIRE,
                               __HIP_MEMORY_SCOPE_AGENT) == g) {
        __builtin_amdgcn_s_sleep(1);
      }
    }
  }
  __syncthreads();
  __threadfence();
}

// ---------------- counts, threshold; zero step-0 rows + sos one-hot --------
__global__ __launch_bounds__(256) void k_cnt(
    const int* __restrict__ pad, const int* __restrict__ pmask,
    const int* __restrict__ sosp,
    float* __restrict__ cntp, float* __restrict__ thr, float* __restrict__ out) {
  __shared__ int r1[256], r2[256];
  int b = blockIdx.x, tid = threadIdx.x;
  float4* orow4 = (float4*)(out + (size_t)b*VV);
  float4 z = {0.f,0.f,0.f,0.f};
  for (int i = tid; i < VV/4; i += 256) orow4[i] = z;
  int cp = 0, cq = 0;
  for (int n = tid; n < NN; n += 256) { cp += pad[b*NN+n]; cq += pmask[b*NN+n]; }
  r1[tid] = cp; r2[tid] = cq; __syncthreads();
  for (int st = 128; st; st >>= 1) {
    if (tid < st) { r1[tid] += r1[tid+st]; r2[tid] += r2[tid+st]; }
    __syncthreads();
  }
  if (tid == 0) {
    cntp[b] = (float)r1[0];
    thr[b]  = 1.0f/(float)r2[0];
    out[(size_t)b*VV + sosp[0]] = 1.0f;
  }
}

// ---------------- h0 mean: partial sums (branch-free) ----------------------
__global__ __launch_bounds__(128) void k_meanpart(
    const float* __restrict__ enc, const int* __restrict__ pad,
    float* __restrict__ hpart) {
  int b = blockIdx.x, ch = blockIdx.y, kq = threadIdx.x;
  int n0 = ch*32;
  float4 acc = {0.f,0.f,0.f,0.f};
#pragma unroll 8
  for (int r = 0; r < 32; r++) {
    int n = n0 + r;
    float msk = (float)pad[b*NN + n];
    float4 v = *(const float4*)(enc + ((size_t)(b*NN + n))*DD + kq*4);
    acc.x += msk*v.x; acc.y += msk*v.y; acc.z += msk*v.z; acc.w += msk*v.w;
  }
  *(float4*)(hpart + ((size_t)(b*64 + ch))*DD + kq*4) = acc;
}

__global__ __launch_bounds__(128) void k_meanfin(
    const float* __restrict__ hpart, const float* __restrict__ cntp,
    float* __restrict__ h0, float* __restrict__ c) {
  int b = blockIdx.x, kq = threadIdx.x;
  float4 acc = {0.f,0.f,0.f,0.f};
  for (int ch = 0; ch < 64; ch++) {
    float4 v = *(const float4*)(hpart + ((size_t)(b*64 + ch))*DD + kq*4);
    acc.x += v.x; acc.y += v.y; acc.z += v.z; acc.w += v.w;
  }
  float ic = 1.0f/cntp[b];
  acc.x *= ic; acc.y *= ic; acc.z *= ic; acc.w *= ic;
  *(float4*)(h0 + b*DD + kq*4) = acc;
  *(float4*)(c  + b*DD + kq*4) = acc;
}

// ---------------- G0[m,r] = emb[tok_m].Wih[r] + bih[r]+bhh[r] --------------
// grid (64 r-tiles of 32, 31 m-groups) = 1984 blocks -> ~7.7 blocks/CU so the
// compiler's per-iteration reloads are hidden by TLP.
__global__ __launch_bounds__(256) void k_g0(
    const float* __restrict__ emb, const float* __restrict__ Wih,
    const float* __restrict__ bih, const float* __restrict__ bhh,
    const int* __restrict__ target, const int* __restrict__ sosp,
    float* __restrict__ G0) {
  int nt = blockIdx.x, mg = blockIdx.y;
  int w = threadIdx.x>>6, lane = threadIdx.x&63;
  int m0 = mg*32 + w*8;
  float4 x0[8], x1[8];
#pragma unroll
  for (int j = 0; j < 8; j++) {
    int m = m0 + j, s = m >> 5, bb = m & 31;
    int tok = (s == 0) ? sosp[0] : target[s*BB + bb];
    const float* xp = emb + (size_t)tok*DD + lane*4;
    x0[j] = *(const float4*)xp;
    x1[j] = *(const float4*)(xp + 256);
  }
  int r0 = nt*32;
#pragma unroll 2
  for (int i = 0; i < 32; i++) {
    int r = r0 + i;
    const float* wp = Wih + (size_t)r*DD + lane*4;
    float4 w0 = *(const float4*)wp, w1 = *(const float4*)(wp + 256);
    float a0 = dot4(w0,x0[0]) + dot4(w1,x1[0]);
    float a1 = dot4(w0,x0[1]) + dot4(w1,x1[1]);
    float a2 = dot4(w0,x0[2]) + dot4(w1,x1[2]);
    float a3 = dot4(w0,x0[3]) + dot4(w1,x1[3]);
    float a4 = dot4(w0,x0[4]) + dot4(w1,x1[4]);
    float a5 = dot4(w0,x0[5]) + dot4(w1,x1[5]);
    float a6 = dot4(w0,x0[6]) + dot4(w1,x1[6]);
    float a7 = dot4(w0,x0[7]) + dot4(w1,x1[7]);
    float v = red8(a0,a1,a2,a3,a4,a5,a6,a7,lane) + bih[r] + bhh[r];
    if (lane < 8) G0[(size_t)(m0 + lane)*2048 + r] = v;
  }
}

// ---------------- persistent LSTM: all 31 steps, grid barrier between ------
// 256 blocks x 512 threads. Block bi owns d-cols {2bi,2bi+1} (8 gate rows).
// Wave w handles b in {4w..4w+3}. c lives in registers of tid<64.
__global__ __launch_bounds__(512) void k_lstm_persist(
    const float* __restrict__ h0, const float* __restrict__ Whh,
    const float* __restrict__ G0, float* __restrict__ H,
    int* __restrict__ sync) {
  __shared__ float g[BB*8];
  int bi = blockIdx.x, d0 = bi*2;
  int tid = threadIdx.x;
  int w = tid>>6, lane = tid&63;
  int cb = tid>>1, cdd = tid&1;
  float creg = 0.f;
  if (tid < 64) creg = h0[cb*DD + d0 + cdd];
  int* cnt = sync; int* gen = sync + 1;
  float4 W0[8], W1[8];
#pragma unroll
  for (int j = 0; j < 8; j++) {
    int r = (j>>1)*DD + d0 + (j&1);
    const float* wp = Whh + (size_t)r*DD + lane*4;
    W0[j] = *(const float4*)wp; W1[j] = *(const float4*)(wp + 256);
  }
  for (int s = 0; s < NSTEP; s++) {
    const float* hin = (s == 0) ? h0 : (H + (size_t)(s-1)*BB*DD);
#pragma unroll
    for (int bb = 0; bb < 4; bb++) {
      int b = w*4 + bb;
      const float* hp = hin + b*DD + lane*4;
      float4 h0v = *(const float4*)hp, h1v = *(const float4*)(hp + 256);
      float a0 = dot4(h0v,W0[0]) + dot4(h1v,W1[0]);
      float a1 = dot4(h0v,W0[1]) + dot4(h1v,W1[1]);
      float a2 = dot4(h0v,W0[2]) + dot4(h1v,W1[2]);
      float a3 = dot4(h0v,W0[3]) + dot4(h1v,W1[3]);
      float a4 = dot4(h0v,W0[4]) + dot4(h1v,W1[4]);
      float a5 = dot4(h0v,W0[5]) + dot4(h1v,W1[5]);
      float a6 = dot4(h0v,W0[6]) + dot4(h1v,W1[6]);
      float a7 = dot4(h0v,W0[7]) + dot4(h1v,W1[7]);
      float v = red8(a0,a1,a2,a3,a4,a5,a6,a7,lane);
      if (lane < 8) g[b*8 + lane] = v;
    }
    __syncthreads();
    if (tid < 64) {
      const float* G = G0 + (size_t)s*BB*2048 + (size_t)cb*2048 + d0 + cdd;
      float gi = g[cb*8 + 0 + cdd] + G[0];
      float gf = g[cb*8 + 2 + cdd] + G[512];
      float gg = g[cb*8 + 4 + cdd] + G[1024];
      float go = g[cb*8 + 6 + cdd] + G[1536];
      float cn = sigm(gf)*creg + sigm(gi)*tanhf(gg);
      float hn = sigm(go)*tanhf(cn);
      creg = cn;
      H[(size_t)s*BB*DD + cb*DD + d0 + cdd] = hn;
    }
    grid_barrier(cnt, gen, gridDim.x);
  }
}

// ---------------- Q[m,r] = H[m].Watt[r], all steps -------------------------
// grid (32 r-tiles of 16, 31 m-groups) = 992 blocks.
__global__ __launch_bounds__(256) void k_qallw(
    const float* __restrict__ H, const float* __restrict__ Watt,
    float* __restrict__ Q) {
  int nt = blockIdx.x, mg = blockIdx.y;
  int w = threadIdx.x>>6, lane = threadIdx.x&63;
  int m0 = mg*32 + w*8;
  float4 x0[8], x1[8];
#pragma unroll
  for (int j = 0; j < 8; j++) {
    const float* xp = H + (size_t)(m0 + j)*DD + lane*4;
    x0[j] = *(const float4*)xp; x1[j] = *(const float4*)(xp + 256);
  }
  int r0 = nt*16;
#pragma unroll 2
  for (int i = 0; i < 16; i++) {
    int r = r0 + i;
    const float* wp = Watt + (size_t)r*DD + lane*4;
    float4 w0 = *(const float4*)wp, w1 = *(const float4*)(wp + 256);
    float a0 = dot4(w0,x0[0]) + dot4(w1,x1[0]);
    float a1 = dot4(w0,x0[1]) + dot4(w1,x1[1]);
    float a2 = dot4(w0,x0[2]) + dot4(w1,x1[2]);
    float a3 = dot4(w0,x0[3]) + dot4(w1,x1[3]);
    float a4 = dot4(w0,x0[4]) + dot4(w1,x1[4]);
    float a5 = dot4(w0,x0[5]) + dot4(w1,x1[5]);
    float a6 = dot4(w0,x0[6]) + dot4(w1,x1[6]);
    float a7 = dot4(w0,x0[7]) + dot4(w1,x1[7]);
    float v = red8(a0,a1,a2,a3,a4,a5,a6,a7,lane);
    if (lane < 8) Q[(size_t)(m0 + lane)*DD + r] = v;
  }
}

// ---------------- S[s,b,n] = enc[b,n,:].Q[s*32+b,:] ------------------------
// grid (64 n-tiles of 32, 32 b) = 2048 blocks.
__global__ __launch_bounds__(256) void k_scores3(
    const float* __restrict__ enc, const float* __restrict__ Q,
    float* __restrict__ S) {
  int nt = blockIdx.x, b = blockIdx.y;
  int w = threadIdx.x>>6, lane = threadIdx.x&63;
  int s0 = w*8;
  float4 q0[8], q1[8];
#pragma unroll
  for (int j = 0; j < 8; j++) {
    const float* qp = Q + (size_t)((s0 + j)*BB + b)*DD + lane*4;
    q0[j] = *(const float4*)qp; q1[j] = *(const float4*)(qp + 256);
  }
  int n0 = nt*32;
  int sl = s0 + (lane & 7);
#pragma unroll 2
  for (int i = 0; i < 32; i++) {
    int n = n0 + i;
    const float* ep = enc + ((size_t)(b*NN + n))*DD + lane*4;
    float4 e0 = *(const float4*)ep, e1 = *(const float4*)(ep + 256);
    float a0 = dot4(e0,q0[0]) + dot4(e1,q1[0]);
    float a1 = dot4(e0,q0[1]) + dot4(e1,q1[1]);
    float a2 = dot4(e0,q0[2]) + dot4(e1,q1[2]);
    float a3 = dot4(e0,q0[3]) + dot4(e1,q1[3]);
    float a4 = dot4(e0,q0[4]) + dot4(e1,q1[4]);
    float a5 = dot4(e0,q0[5]) + dot4(e1,q1[5]);
    float a6 = dot4(e0,q0[6]) + dot4(e1,q1[6]);
    float a7 = dot4(e0,q0[7]) + dot4(e1,q1[7]);
    float v = red8(a0,a1,a2,a3,a4,a5,a6,a7,lane);
    if (lane < 8 && sl < NSTEP) S[((size_t)sl*BB + b)*NN + n] = v;
  }
}

// ---------------- zero row + masked softmax + threshold + scatter + eos ----
__global__ __launch_bounds__(256) void k_scatter2(
    const float* __restrict__ S, const int* __restrict__ pmask,
    const int* __restrict__ tok, const float* __restrict__ thr,
    const int* __restrict__ eosp, float* __restrict__ out) {
  __shared__ float red[256];
  __shared__ float ex[NN];
  int s = blockIdx.x, b = blockIdx.y, tid = threadIdx.x;
  float* orow = out + ((size_t)(s+1)*BB + b)*VV;
  float4 z = {0.f,0.f,0.f,0.f};
  float4* orow4 = (float4*)orow;
  for (int i = tid; i < VV/4; i += 256) orow4[i] = z;
  const float* sr = S + ((size_t)s*BB + b)*NN;
  const int* pm = pmask + b*NN;
  float m = -3.4e38f;
  for (int n = tid; n < NN; n += 256) if (pm[n]) m = fmaxf(m, sr[n]);
  red[tid] = m; __syncthreads();
  for (int st = 128; st; st >>= 1) {
    if (tid < st) red[tid] = fmaxf(red[tid], red[tid+st]);
    __syncthreads();
  }
  float smax = red[0]; __syncthreads();
  float sum = 0.f;
  for (int n = tid; n < NN; n += 256) {
    float e = pm[n] ? expf(sr[n] - smax) : 0.f;
    ex[n] = e; sum += e;
  }
  red[tid] = sum; __syncthreads();
  for (int st = 128; st; st >>= 1) {
    if (tid < st) red[tid] += red[tid+st];
    __syncthreads();
  }
  float inv = 1.0f/red[0];
  float th = thr[b];
  float keep = 0.f;
  for (int n = tid; n < NN; n += 256) {
    float p = ex[n]*inv;
    if (p >= th) { atomicAdd(orow + tok[b*NN + n], p); keep += p; }
  }
  __syncthreads();
  red[tid] = keep; __syncthreads();
  for (int st = 128; st; st >>= 1) {
    if (tid < st) red[tid] += red[tid+st];
    __syncthreads();
  }
  if (tid == 0) orow[eosp[0]] = 1.0f - red[0];
}

extern "C" void kernel_launch(void* const* d_in, const int* in_sizes, int n_in,
                              void* d_out, int out_size, void* d_ws, size_t ws_size,
                              hipStream_t stream) {
  const float* enc   = (const float*)d_in[0];
  const float* emb   = (const float*)d_in[1];
  const float* Wih   = (const float*)d_in[2];
  const float* Whh   = (const float*)d_in[3];
  const float* bih   = (const float*)d_in[4];
  const float* bhh   = (const float*)d_in[5];
  const float* Watt  = (const float*)d_in[6];
  const int*   pad   = (const int*)d_in[7];
  const int*   pmask = (const int*)d_in[8];
  const int*   tok   = (const int*)d_in[9];
  const int*   target= (const int*)d_in[10];
  const int*   sosp  = (const int*)d_in[11];
  const int*   eosp  = (const int*)d_in[12];
  float* out = (float*)d_out;

  // workspace layout: [sync 64 ints][floats...]; hpart aliases G0.
  int*   sync = (int*)d_ws;
  float* w    = (float*)d_ws + 64;
  float* c    = w;                          // 32*512
  float* h0   = c    + BB*DD;               // 32*512
  float* H    = h0   + BB*DD;               // 31*32*512
  float* Q    = H    + NSTEP*BB*DD;         // padded: 32*32*512
  float* S    = Q    + 32*BB*DD;            // 31*32*2048
  float* G0   = S    + (size_t)NSTEP*BB*NN; // 992*2048
  float* cntp = G0   + (size_t)992*2048;    // 32
  float* thr  = cntp + 32;                  // 32
  float* hpart = G0;                        // 32*64*512 (alias, pre-G0 only)

  hipMemsetAsync(sync, 0, 64*sizeof(int), stream);
  k_cnt<<<32, 256, 0, stream>>>(pad, pmask, sosp, cntp, thr, out);
  k_meanpart<<<dim3(32,64), 128, 0, stream>>>(enc, pad, hpart);
  k_meanfin<<<32, 128, 0, stream>>>(hpart, cntp, h0, c);

  k_g0<<<dim3(64,31), 256, 0, stream>>>(emb, Wih, bih, bhh, target, sosp, G0);

  k_lstm_persist<<<256, 512, 0, stream>>>(h0, Whh, G0, H, sync);

  k_qallw<<<dim3(32,31), 256, 0, stream>>>(H, Watt, Q);
  k_scores3<<<dim3(64,32), 256, 0, stream>>>(enc, Q, S);
  k_scatter2<<<dim3(NSTEP,32), 256, 0, stream>>>(S, pmask, tok, thr, eosp, out);
}

// Round 6
// 663.930 us; speedup vs baseline: 5.0964x; 5.0964x over previous
//
#include <hip/hip_runtime.h>
#include <math.h>

#define BB 32
#define NN 2048
#define DD 512
#define VV 32000
#define NSTEP 31

__device__ inline float sigm(float x){ return 1.0f/(1.0f+expf(-x)); }
__device__ inline float dot4(float4 a, float4 b){
  return a.x*b.x + a.y*b.y + a.z*b.z + a.w*b.w;
}

// Merged 8-way wave reduction: returns, in every lane, the full 64-lane sum
// of a_{lane&7}.
__device__ inline float red8(float a0,float a1,float a2,float a3,
                             float a4,float a5,float a6,float a7,int lane){
  float m01 = ((lane&1)? a1:a0) + __shfl_xor(((lane&1)? a0:a1),1,64);
  float m23 = ((lane&1)? a3:a2) + __shfl_xor(((lane&1)? a2:a3),1,64);
  float m45 = ((lane&1)? a5:a4) + __shfl_xor(((lane&1)? a4:a5),1,64);
  float m67 = ((lane&1)? a7:a6) + __shfl_xor(((lane&1)? a6:a7),1,64);
  float m03 = ((lane&2)? m23:m01) + __shfl_xor(((lane&2)? m01:m23),2,64);
  float m47 = ((lane&2)? m67:m45) + __shfl_xor(((lane&2)? m45:m67),2,64);
  float m   = ((lane&4)? m47:m03) + __shfl_xor(((lane&4)? m03:m47),4,64);
  m += __shfl_xor(m,8,64); m += __shfl_xor(m,16,64); m += __shfl_xor(m,32,64);
  return m;
}

// ---------------- counts, threshold; zero step-0 rows + sos one-hot --------
__global__ __launch_bounds__(256) void k_cnt(
    const int* __restrict__ pad, const int* __restrict__ pmask,
    const int* __restrict__ sosp,
    float* __restrict__ cntp, float* __restrict__ thr, float* __restrict__ out) {
  __shared__ int r1[256], r2[256];
  int b = blockIdx.x, tid = threadIdx.x;
  float4* orow4 = (float4*)(out + (size_t)b*VV);
  float4 z = {0.f,0.f,0.f,0.f};
  for (int i = tid; i < VV/4; i += 256) orow4[i] = z;
  int cp = 0, cq = 0;
  for (int n = tid; n < NN; n += 256) { cp += pad[b*NN+n]; cq += pmask[b*NN+n]; }
  r1[tid] = cp; r2[tid] = cq; __syncthreads();
  for (int st = 128; st; st >>= 1) {
    if (tid < st) { r1[tid] += r1[tid+st]; r2[tid] += r2[tid+st]; }
    __syncthreads();
  }
  if (tid == 0) {
    cntp[b] = (float)r1[0];
    thr[b]  = 1.0f/(float)r2[0];
    out[(size_t)b*VV + sosp[0]] = 1.0f;
  }
}

// ---------------- h0 mean: partial sums (branch-free) ----------------------
__global__ __launch_bounds__(128) void k_meanpart(
    const float* __restrict__ enc, const int* __restrict__ pad,
    float* __restrict__ hpart) {
  int b = blockIdx.x, ch = blockIdx.y, kq = threadIdx.x;
  int n0 = ch*32;
  float4 acc = {0.f,0.f,0.f,0.f};
#pragma unroll 8
  for (int r = 0; r < 32; r++) {
    int n = n0 + r;
    float msk = (float)pad[b*NN + n];
    float4 v = *(const float4*)(enc + ((size_t)(b*NN + n))*DD + kq*4);
    acc.x += msk*v.x; acc.y += msk*v.y; acc.z += msk*v.z; acc.w += msk*v.w;
  }
  *(float4*)(hpart + ((size_t)(b*64 + ch))*DD + kq*4) = acc;
}

__global__ __launch_bounds__(128) void k_meanfin(
    const float* __restrict__ hpart, const float* __restrict__ cntp,
    float* __restrict__ h0, float* __restrict__ c) {
  int b = blockIdx.x, kq = threadIdx.x;
  float4 acc = {0.f,0.f,0.f,0.f};
  for (int ch = 0; ch < 64; ch++) {
    float4 v = *(const float4*)(hpart + ((size_t)(b*64 + ch))*DD + kq*4);
    acc.x += v.x; acc.y += v.y; acc.z += v.z; acc.w += v.w;
  }
  float ic = 1.0f/cntp[b];
  acc.x *= ic; acc.y *= ic; acc.z *= ic; acc.w *= ic;
  *(float4*)(h0 + b*DD + kq*4) = acc;
  *(float4*)(c  + b*DD + kq*4) = acc;
}

// ---------------- G0[m,r] = emb[tok_m].Wih[r] + bih[r]+bhh[r] --------------
// grid (64 r-tiles of 32, 31 m-groups) = 1984 blocks -> ~7.7 blocks/CU; the
// compiler's per-iteration reloads are L1-hot and hidden by TLP.
__global__ __launch_bounds__(256) void k_g0(
    const float* __restrict__ emb, const float* __restrict__ Wih,
    const float* __restrict__ bih, const float* __restrict__ bhh,
    const int* __restrict__ target, const int* __restrict__ sosp,
    float* __restrict__ G0) {
  int nt = blockIdx.x, mg = blockIdx.y;
  int w = threadIdx.x>>6, lane = threadIdx.x&63;
  int m0 = mg*32 + w*8;
  float4 x0[8], x1[8];
#pragma unroll
  for (int j = 0; j < 8; j++) {
    int m = m0 + j, s = m >> 5, bb = m & 31;
    int tok = (s == 0) ? sosp[0] : target[s*BB + bb];
    const float* xp = emb + (size_t)tok*DD + lane*4;
    x0[j] = *(const float4*)xp;
    x1[j] = *(const float4*)(xp + 256);
  }
  int r0 = nt*32;
#pragma unroll 2
  for (int i = 0; i < 32; i++) {
    int r = r0 + i;
    const float* wp = Wih + (size_t)r*DD + lane*4;
    float4 w0 = *(const float4*)wp, w1 = *(const float4*)(wp + 256);
    float a0 = dot4(w0,x0[0]) + dot4(w1,x1[0]);
    float a1 = dot4(w0,x0[1]) + dot4(w1,x1[1]);
    float a2 = dot4(w0,x0[2]) + dot4(w1,x1[2]);
    float a3 = dot4(w0,x0[3]) + dot4(w1,x1[3]);
    float a4 = dot4(w0,x0[4]) + dot4(w1,x1[4]);
    float a5 = dot4(w0,x0[5]) + dot4(w1,x1[5]);
    float a6 = dot4(w0,x0[6]) + dot4(w1,x1[6]);
    float a7 = dot4(w0,x0[7]) + dot4(w1,x1[7]);
    float v = red8(a0,a1,a2,a3,a4,a5,a6,a7,lane) + bih[r] + bhh[r];
    if (lane < 8) G0[(size_t)(m0 + lane)*2048 + r] = v;
  }
}

// ---------------- per-step: gates = G0[s] + h@Whh^T; LSTM pointwise --------
// 256 blocks x 512 threads (8 waves). Block bi owns d-cols {2bi,2bi+1}
// (8 gate rows); wave w handles b in {4w..4w+3}. Launch-per-step: grid-wide
// sync via kernel boundary (device barriers are poisonous on 8-XCD gfx950).
__global__ __launch_bounds__(512) void k_hstep(
    const float* __restrict__ hin, const float* __restrict__ Whh,
    const float* __restrict__ G0s, float* __restrict__ c,
    float* __restrict__ hout) {
  __shared__ float g[BB*8];
  int bi = blockIdx.x, d0 = bi*2;
  int tid = threadIdx.x;
  int w = tid>>6, lane = tid&63;
  float4 W0[8], W1[8];
#pragma unroll
  for (int j = 0; j < 8; j++) {
    int r = (j>>1)*DD + d0 + (j&1);
    const float* wp = Whh + (size_t)r*DD + lane*4;
    W0[j] = *(const float4*)wp; W1[j] = *(const float4*)(wp + 256);
  }
#pragma unroll
  for (int bb = 0; bb < 4; bb++) {
    int b = w*4 + bb;
    const float* hp = hin + b*DD + lane*4;
    float4 h0v = *(const float4*)hp, h1v = *(const float4*)(hp + 256);
    float a0 = dot4(h0v,W0[0]) + dot4(h1v,W1[0]);
    float a1 = dot4(h0v,W0[1]) + dot4(h1v,W1[1]);
    float a2 = dot4(h0v,W0[2]) + dot4(h1v,W1[2]);
    float a3 = dot4(h0v,W0[3]) + dot4(h1v,W1[3]);
    float a4 = dot4(h0v,W0[4]) + dot4(h1v,W1[4]);
    float a5 = dot4(h0v,W0[5]) + dot4(h1v,W1[5]);
    float a6 = dot4(h0v,W0[6]) + dot4(h1v,W1[6]);
    float a7 = dot4(h0v,W0[7]) + dot4(h1v,W1[7]);
    float v = red8(a0,a1,a2,a3,a4,a5,a6,a7,lane);
    if (lane < 8) g[b*8 + lane] = v;
  }
  __syncthreads();
  if (tid < 64) {
    int b = tid>>1, dd = tid&1;
    const float* G = G0s + (size_t)b*2048 + d0 + dd;
    float gi = g[b*8 + 0 + dd] + G[0];
    float gf = g[b*8 + 2 + dd] + G[512];
    float gg = g[b*8 + 4 + dd] + G[1024];
    float go = g[b*8 + 6 + dd] + G[1536];
    int ci = b*DD + d0 + dd;
    float cn = sigm(gf)*c[ci] + sigm(gi)*tanhf(gg);
    float hn = sigm(go)*tanhf(cn);
    c[ci] = cn; hout[ci] = hn;
  }
}

// ---------------- Q[m,r] = H[m].Watt[r], all steps -------------------------
// grid (32 r-tiles of 16, 31 m-groups) = 992 blocks.
__global__ __launch_bounds__(256) void k_qallw(
    const float* __restrict__ H, const float* __restrict__ Watt,
    float* __restrict__ Q) {
  int nt = blockIdx.x, mg = blockIdx.y;
  int w = threadIdx.x>>6, lane = threadIdx.x&63;
  int m0 = mg*32 + w*8;
  float4 x0[8], x1[8];
#pragma unroll
  for (int j = 0; j < 8; j++) {
    const float* xp = H + (size_t)(m0 + j)*DD + lane*4;
    x0[j] = *(const float4*)xp; x1[j] = *(const float4*)(xp + 256);
  }
  int r0 = nt*16;
#pragma unroll 2
  for (int i = 0; i < 16; i++) {
    int r = r0 + i;
    const float* wp = Watt + (size_t)r*DD + lane*4;
    float4 w0 = *(const float4*)wp, w1 = *(const float4*)(wp + 256);
    float a0 = dot4(w0,x0[0]) + dot4(w1,x1[0]);
    float a1 = dot4(w0,x0[1]) + dot4(w1,x1[1]);
    float a2 = dot4(w0,x0[2]) + dot4(w1,x1[2]);
    float a3 = dot4(w0,x0[3]) + dot4(w1,x1[3]);
    float a4 = dot4(w0,x0[4]) + dot4(w1,x1[4]);
    float a5 = dot4(w0,x0[5]) + dot4(w1,x1[5]);
    float a6 = dot4(w0,x0[6]) + dot4(w1,x1[6]);
    float a7 = dot4(w0,x0[7]) + dot4(w1,x1[7]);
    float v = red8(a0,a1,a2,a3,a4,a5,a6,a7,lane);
    if (lane < 8) Q[(size_t)(m0 + lane)*DD + r] = v;
  }
}

// ---------------- S[s,b,n] = enc[b,n,:].Q[s*32+b,:] ------------------------
// grid (64 n-tiles of 32, 32 b) = 2048 blocks.
__global__ __launch_bounds__(256) void k_scores3(
    const float* __restrict__ enc, const float* __restrict__ Q,
    float* __restrict__ S) {
  int nt = blockIdx.x, b = blockIdx.y;
  int w = threadIdx.x>>6, lane = threadIdx.x&63;
  int s0 = w*8;
  float4 q0[8], q1[8];
#pragma unroll
  for (int j = 0; j < 8; j++) {
    const float* qp = Q + (size_t)((s0 + j)*BB + b)*DD + lane*4;
    q0[j] = *(const float4*)qp; q1[j] = *(const float4*)(qp + 256);
  }
  int n0 = nt*32;
  int sl = s0 + (lane & 7);
#pragma unroll 2
  for (int i = 0; i < 32; i++) {
    int n = n0 + i;
    const float* ep = enc + ((size_t)(b*NN + n))*DD + lane*4;
    float4 e0 = *(const float4*)ep, e1 = *(const float4*)(ep + 256);
    float a0 = dot4(e0,q0[0]) + dot4(e1,q1[0]);
    float a1 = dot4(e0,q0[1]) + dot4(e1,q1[1]);
    float a2 = dot4(e0,q0[2]) + dot4(e1,q1[2]);
    float a3 = dot4(e0,q0[3]) + dot4(e1,q1[3]);
    float a4 = dot4(e0,q0[4]) + dot4(e1,q1[4]);
    float a5 = dot4(e0,q0[5]) + dot4(e1,q1[5]);
    float a6 = dot4(e0,q0[6]) + dot4(e1,q1[6]);
    float a7 = dot4(e0,q0[7]) + dot4(e1,q1[7]);
    float v = red8(a0,a1,a2,a3,a4,a5,a6,a7,lane);
    if (lane < 8 && sl < NSTEP) S[((size_t)sl*BB + b)*NN + n] = v;
  }
}

// ---------------- zero row + masked softmax + threshold + scatter + eos ----
__global__ __launch_bounds__(256) void k_scatter2(
    const float* __restrict__ S, const int* __restrict__ pmask,
    const int* __restrict__ tok, const float* __restrict__ thr,
    const int* __restrict__ eosp, float* __restrict__ out) {
  __shared__ float red[256];
  __shared__ float ex[NN];
  int s = blockIdx.x, b = blockIdx.y, tid = threadIdx.x;
  float* orow = out + ((size_t)(s+1)*BB + b)*VV;
  float4 z = {0.f,0.f,0.f,0.f};
  float4* orow4 = (float4*)orow;
  for (int i = tid; i < VV/4; i += 256) orow4[i] = z;
  const float* sr = S + ((size_t)s*BB + b)*NN;
  const int* pm = pmask + b*NN;
  float m = -3.4e38f;
  for (int n = tid; n < NN; n += 256) if (pm[n]) m = fmaxf(m, sr[n]);
  red[tid] = m; __syncthreads();
  for (int st = 128; st; st >>= 1) {
    if (tid < st) red[tid] = fmaxf(red[tid], red[tid+st]);
    __syncthreads();
  }
  float smax = red[0]; __syncthreads();
  float sum = 0.f;
  for (int n = tid; n < NN; n += 256) {
    float e = pm[n] ? expf(sr[n] - smax) : 0.f;
    ex[n] = e; sum += e;
  }
  red[tid] = sum; __syncthreads();
  for (int st = 128; st; st >>= 1) {
    if (tid < st) red[tid] += red[tid+st];
    __syncthreads();
  }
  float inv = 1.0f/red[0];
  float th = thr[b];
  float keep = 0.f;
  for (int n = tid; n < NN; n += 256) {
    float p = ex[n]*inv;
    if (p >= th) { atomicAdd(orow + tok[b*NN + n], p); keep += p; }
  }
  __syncthreads();
  red[tid] = keep; __syncthreads();
  for (int st = 128; st; st >>= 1) {
    if (tid < st) red[tid] += red[tid+st];
    __syncthreads();
  }
  if (tid == 0) orow[eosp[0]] = 1.0f - red[0];
}

extern "C" void kernel_launch(void* const* d_in, const int* in_sizes, int n_in,
                              void* d_out, int out_size, void* d_ws, size_t ws_size,
                              hipStream_t stream) {
  const float* enc   = (const float*)d_in[0];
  const float* emb   = (const float*)d_in[1];
  const float* Wih   = (const float*)d_in[2];
  const float* Whh   = (const float*)d_in[3];
  const float* bih   = (const float*)d_in[4];
  const float* bhh   = (const float*)d_in[5];
  const float* Watt  = (const float*)d_in[6];
  const int*   pad   = (const int*)d_in[7];
  const int*   pmask = (const int*)d_in[8];
  const int*   tok   = (const int*)d_in[9];
  const int*   target= (const int*)d_in[10];
  const int*   sosp  = (const int*)d_in[11];
  const int*   eosp  = (const int*)d_in[12];
  float* out = (float*)d_out;

  // workspace layout (floats), ~20.5 MB. hpart aliases G0 (used only before it).
  float* w    = (float*)d_ws;
  float* c    = w;                          // 32*512
  float* h0   = c    + BB*DD;               // 32*512
  float* H    = h0   + BB*DD;               // 31*32*512
  float* Q    = H    + NSTEP*BB*DD;         // padded: 32*32*512
  float* S    = Q    + 32*BB*DD;            // 31*32*2048
  float* G0   = S    + (size_t)NSTEP*BB*NN; // 992*2048
  float* cntp = G0   + (size_t)992*2048;    // 32
  float* thr  = cntp + 32;                  // 32
  float* hpart = G0;                        // 32*64*512 (alias, pre-G0 only)

  k_cnt<<<32, 256, 0, stream>>>(pad, pmask, sosp, cntp, thr, out);
  k_meanpart<<<dim3(32,64), 128, 0, stream>>>(enc, pad, hpart);
  k_meanfin<<<32, 128, 0, stream>>>(hpart, cntp, h0, c);

  k_g0<<<dim3(64,31), 256, 0, stream>>>(emb, Wih, bih, bhh, target, sosp, G0);

  for (int s = 0; s < NSTEP; s++) {
    const float* hin = (s == 0) ? h0 : (H + (size_t)(s-1)*BB*DD);
    k_hstep<<<256, 512, 0, stream>>>(hin, Whh, G0 + (size_t)s*BB*2048, c,
                                     H + (size_t)s*BB*DD);
  }

  k_qallw<<<dim3(32,31), 256, 0, stream>>>(H, Watt, Q);
  k_scores3<<<dim3(64,32), 256, 0, stream>>>(enc, Q, S);
  k_scatter2<<<dim3(NSTEP,32), 256, 0, stream>>>(S, pmask, tok, thr, eosp, out);
}